// Round 2
// baseline (436.960 us; speedup 1.0000x reference)
//
#include <hip/hip_runtime.h>
#include <hip/hip_bf16.h>
#include <stdint.h>
#include <type_traits>

// Problem constants (reference: N=16384, F=1024, B=512)
#define N_ROWS 16384
#define F_DIM  1024
#define B_DIM  512
#define K_DIM  1536   // F + B
#define G_DIM  4096   // 4*F
#define NT     24     // K_DIM / 64 K-tiles
#define CB_STR 68     // padded fp32 stride for epilogue LDS tile (68%32==4 -> 2-way max)

typedef __bf16 v8bf __attribute__((ext_vector_type(8)));
typedef float  v4f  __attribute__((ext_vector_type(4)));

typedef const void __attribute__((address_space(1)))* gptr1;
typedef void       __attribute__((address_space(3)))* lptr3;

__device__ __forceinline__ unsigned short f2bf(float x) {
    union { float f; unsigned int u; } c; c.f = x;
    unsigned int u = c.u;
    return (unsigned short)((u + 0x7FFFu + ((u >> 16) & 1u)) >> 16);  // RNE; inputs finite
}

__device__ __forceinline__ float sigmoidf_fast(float x) {
    return 1.f / (1.f + __expf(-x));
}
__device__ __forceinline__ float tanhf_fast(float x) {
    return 1.f - 2.f / (__expf(2.f * x) + 1.f);   // saturates correctly at +/-1
}

// ---------------------------------------------------------------------------
// Merged pack kernel (one dispatch instead of two):
//   blocks [0, N_ROWS)           : A = bf16([h_prev | behavior]) row-major
//   blocks [N_ROWS, N_ROWS+G_DIM): W' = bf16 gate-interleaved [Wh | Wx], b'
// ---------------------------------------------------------------------------
__global__ void pack_all(const float* __restrict__ behavior,
                         const float* __restrict__ h_prev,
                         const float* __restrict__ Wh,
                         const float* __restrict__ Wx,
                         const float* __restrict__ b,
                         unsigned short* __restrict__ A,
                         unsigned short* __restrict__ W,
                         float* __restrict__ bperm) {
    const int blk = blockIdx.x;
    const int col = threadIdx.x * 8;              // 0..1528, never straddles 1024
    const float* src;
    unsigned short* dst;
    if (blk < N_ROWS) {
        src = (col < F_DIM) ? h_prev + (long)blk * F_DIM + col
                            : behavior + (long)blk * B_DIM + (col - F_DIM);
        dst = A + (long)blk * K_DIM + col;
    } else {
        const int gp   = blk - N_ROWS;
        const int gate = gp & 3;
        const int f    = gp >> 2;
        const int g    = gate * F_DIM + f;        // original row in Wh/Wx
        src = (col < F_DIM) ? Wh + (long)g * F_DIM + col
                            : Wx + (long)g * B_DIM + (col - F_DIM);
        dst = W + (long)gp * K_DIM + col;
        if (threadIdx.x == 0) bperm[gp] = b[g];
    }
    float4 lo = *(const float4*)src;
    float4 hi = *(const float4*)(src + 4);
    union { unsigned short u[8]; int4 v; } p;
    p.u[0] = f2bf(lo.x); p.u[1] = f2bf(lo.y); p.u[2] = f2bf(lo.z); p.u[3] = f2bf(lo.w);
    p.u[4] = f2bf(hi.x); p.u[5] = f2bf(hi.y); p.u[6] = f2bf(hi.z); p.u[7] = f2bf(hi.w);
    *(int4*)dst = p.v;
}

// ---------------------------------------------------------------------------
// Fused GEMM (gates = A @ W'^T) + bias + activations + c/h epilogue.
// 256x256 tile, BK=64, 8 waves (2Mx4N), 512 threads. 8-phase-style schedule
// with counted vmcnt (T3+T4), setprio around MFMA clusters (T5), swizzled
// LDS (T2), XCD-bijective block swizzle (T1).
//
// LDS (128 KiB dynamic): A[buf2][khalf2][row256][64B] | B same at +64KiB.
// Within a k-half plane, 16B slot d of row r holds global k-chunk d^(r&3)
// (source pre-swizzled, LDS dest linear for global_load_lds). With the 64B
// row stride this gives exactly 8 accesses/bank on every ds_read_b128 (floor).
//
// Staging units per K-tile: (A,kh0)(B,kh0)(A,kh1)(B,kh1), 2 loads/thread each,
// issued one per phase for tile t+1 while computing tile t. vmcnt(4) at
// phases 1 and 3 retires exactly the 2 units the next phases need; 4 loads
// always stay in flight across the barriers (never drain in main loop).
// ---------------------------------------------------------------------------
__global__ __launch_bounds__(512, 2) void lstm_gemm(
    const unsigned short* __restrict__ A,   // [N_ROWS][K_DIM] bf16
    const unsigned short* __restrict__ W,   // [G_DIM][K_DIM]  bf16, interleaved
    const float* __restrict__ bperm,        // [G_DIM]
    const float* __restrict__ c_prev,       // [N_ROWS][F_DIM]
    float* __restrict__ out)                // [N_ROWS][F_DIM]
{
    extern __shared__ char smem[];          // 131072 bytes

    // XCD-aware bijective swizzle (1024 blocks, 1024%8==0). Row-blocks walk
    // fastest: each XCD chunk of 128 blocks = 2 W-panels (1.5 MB, L2-fits)
    // reused across 64 A row-blocks.
    const int bid = blockIdx.x;                   // 0..1023
    const int s   = (bid & 7) * 128 + (bid >> 3);
    const int m0  = (s & 63) << 8;                // row-block * 256
    const int n0  = (s >> 6) << 8;                // gate-block * 256

    const int tid  = threadIdx.x;
    const int lane = tid & 63;
    const int wave = tid >> 6;
    const int wmi  = wave >> 2;                   // 0..1
    const int wni  = wave & 3;                    // 0..3
    const int lrow = lane & 15;
    const int quad = lane >> 4;

    // per-lane fragment byte offsets within a [256][64B] k-half plane
    const int ar   = wmi * 128 + lrow;            // + mt*16 (doesn't change ar&3)
    const int aoff = ar * 64 + ((quad ^ (ar & 3)) << 4);
    const int br   = wni * 64 + lrow;             // + nt*16
    const int boff = br * 64 + ((quad ^ (br & 3)) << 4);

    // staging: thread covers 16B slots s0=tid (rows 0..127), s1=tid+512 (128..255)
    const int r0 = tid >> 2,         d0 = tid & 3;
    const int r1 = (tid + 512) >> 2, d1 = tid & 3;   // (tid+512)&3 == tid&3
    const unsigned short* aS0 = A + (long)(m0 + r0) * K_DIM + ((d0 ^ (r0 & 3)) << 3);
    const unsigned short* aS1 = A + (long)(m0 + r1) * K_DIM + ((d1 ^ (r1 & 3)) << 3);
    const unsigned short* wS0 = W + (long)(n0 + r0) * K_DIM + ((d0 ^ (r0 & 3)) << 3);
    const unsigned short* wS1 = W + (long)(n0 + r1) * K_DIM + ((d1 ^ (r1 & 3)) << 3);
    const int du0 = wave * 1024;                  // wave-uniform LDS dest (load 0)
    const int du1 = du0 + 8192;                   // load 1 (rows 128..255)

    v4f acc[8][4] = {};                           // 128 fp32 accum / lane

    // plane index = BUF*2 + khalf; A planes at 0, B planes at +65536
    auto stageA = [&](int plane, int koff) {
        __builtin_amdgcn_global_load_lds((gptr1)(aS0 + koff),
                                         (lptr3)(smem + (plane << 14) + du0), 16, 0, 0);
        __builtin_amdgcn_global_load_lds((gptr1)(aS1 + koff),
                                         (lptr3)(smem + (plane << 14) + du1), 16, 0, 0);
    };
    auto stageB = [&](int plane, int koff) {
        __builtin_amdgcn_global_load_lds((gptr1)(wS0 + koff),
                                         (lptr3)(smem + 65536 + (plane << 14) + du0), 16, 0, 0);
        __builtin_amdgcn_global_load_lds((gptr1)(wS1 + koff),
                                         (lptr3)(smem + 65536 + (plane << 14) + du1), 16, 0, 0);
    };

#define MFMA_BLK(MB)                                                            \
    __builtin_amdgcn_s_setprio(1);                                              \
    _Pragma("unroll")                                                           \
    for (int mt = 0; mt < 4; ++mt)                                              \
        _Pragma("unroll")                                                       \
        for (int nt = 0; nt < 4; ++nt)                                          \
            acc[(MB)*4 + mt][nt] = __builtin_amdgcn_mfma_f32_16x16x32_bf16(     \
                afr[mt], bfr[nt], acc[(MB)*4 + mt][nt], 0, 0, 0);               \
    __builtin_amdgcn_s_setprio(0);

    // One K-tile = 4 phases. kn = k-element offset of the tile being prefetched.
    auto tile = [&](int BUF, int kn, auto pf_tag) {
        constexpr bool PF = decltype(pf_tag)::value;
        const char* A0p = smem + ((BUF * 2 + 0) << 14);
        const char* A1p = smem + ((BUF * 2 + 1) << 14);
        const char* B0p = A0p + 65536;
        const char* B1p = A1p + 65536;
        const int   pb  = (BUF ^ 1) * 2;
        v8bf afr[4], bfr[4];

        // ---- phase 0 : kk=0, mt 0-3 ----
#pragma unroll
        for (int nt = 0; nt < 4; ++nt) bfr[nt] = *(const v8bf*)(B0p + nt * 1024 + boff);
#pragma unroll
        for (int mt = 0; mt < 4; ++mt) afr[mt] = *(const v8bf*)(A0p + mt * 1024 + aoff);
        if constexpr (PF) stageA(pb + 0, kn);
        __builtin_amdgcn_s_barrier();
        asm volatile("s_waitcnt lgkmcnt(0)" ::: "memory");
        MFMA_BLK(0)
        __builtin_amdgcn_s_barrier();

        // ---- phase 1 : kk=0, mt 4-7 (reuse bfr) ----
#pragma unroll
        for (int mt = 0; mt < 4; ++mt) afr[mt] = *(const v8bf*)(A0p + (4 + mt) * 1024 + aoff);
        if constexpr (PF) {
            stageB(pb + 0, kn);
            asm volatile("s_waitcnt vmcnt(4)" ::: "memory");  // lands (A,kh1)(B,kh1) of cur tile
        } else {
            asm volatile("s_waitcnt vmcnt(0)" ::: "memory");  // last tile: drain kh1
        }
        __builtin_amdgcn_s_barrier();
        asm volatile("s_waitcnt lgkmcnt(0)" ::: "memory");
        MFMA_BLK(1)
        __builtin_amdgcn_s_barrier();

        // ---- phase 2 : kk=1, mt 0-3 ----
#pragma unroll
        for (int nt = 0; nt < 4; ++nt) bfr[nt] = *(const v8bf*)(B1p + nt * 1024 + boff);
#pragma unroll
        for (int mt = 0; mt < 4; ++mt) afr[mt] = *(const v8bf*)(A1p + mt * 1024 + aoff);
        if constexpr (PF) stageA(pb + 1, kn + 32);
        __builtin_amdgcn_s_barrier();
        asm volatile("s_waitcnt lgkmcnt(0)" ::: "memory");
        MFMA_BLK(0)
        __builtin_amdgcn_s_barrier();

        // ---- phase 3 : kk=1, mt 4-7 ----
#pragma unroll
        for (int mt = 0; mt < 4; ++mt) afr[mt] = *(const v8bf*)(A1p + (4 + mt) * 1024 + aoff);
        if constexpr (PF) {
            stageB(pb + 1, kn + 32);
            asm volatile("s_waitcnt vmcnt(4)" ::: "memory");  // lands (A,kh0)(B,kh0) of next tile
        }
        __builtin_amdgcn_s_barrier();
        asm volatile("s_waitcnt lgkmcnt(0)" ::: "memory");
        MFMA_BLK(1)
        __builtin_amdgcn_s_barrier();
    };

    // prologue: stage tile 0 fully; keep kh1 in flight (vmcnt(4), not 0)
    stageA(0, 0);  stageB(0, 0);
    stageA(1, 32); stageB(1, 32);
    asm volatile("s_waitcnt vmcnt(4)" ::: "memory");
    __builtin_amdgcn_s_barrier();

    int kn = 64;
    for (int t = 0; t < NT - 1; ++t) {
        tile(t & 1, kn, std::true_type{});
        kn += 64;
    }
    tile((NT - 1) & 1, 0, std::false_type{});
#undef MFMA_BLK

    // ---- stage c_prev tile (256 rows x 64 f-cols) into padded LDS, coalesced ----
    float* cbuf = (float*)smem;                   // [256][CB_STR] = 68 KB (reuse GEMM LDS)
    const int fbase = n0 >> 2;
#pragma unroll
    for (int i = 0; i < 8; ++i) {
        const int q  = i * 512 + tid;             // 0..4095 float4-chunks
        const int r  = q >> 4;
        const int c4 = (q & 15) << 2;
        *(float4*)&cbuf[r * CB_STR + c4] =
            *(const float4*)&c_prev[(long)(m0 + r) * F_DIM + fbase + c4];
    }
    __syncthreads();

    // ---- fused epilogue (in-register 4x4 gate transpose, LDS-staged c/h) ----
    const int l3 = lane & 3;
    const int fl = (lane >> 2) & 3;
#pragma unroll
    for (int nt = 0; nt < 4; ++nt) {
        const int   gcol = n0 + wni * 64 + nt * 16 + lrow;
        const float bias = bperm[gcol];
#pragma unroll
        for (int mt = 0; mt < 8; ++mt) {
            float a0 = acc[mt][nt][0] + bias;
            float a1 = acc[mt][nt][1] + bias;
            float a2 = acc[mt][nt][2] + bias;
            float a3 = acc[mt][nt][3] + bias;
            // 4x4 transpose across lane quads: stage 1 (xor 1, reg bit 0)
            float s0 = (lane & 1) ? a0 : a1;
            float s1 = (lane & 1) ? a2 : a3;
            float t0 = __shfl_xor(s0, 1, 64);
            float t1 = __shfl_xor(s1, 1, 64);
            if (lane & 1) { a0 = t0; a2 = t1; } else { a1 = t0; a3 = t1; }
            // stage 2 (xor 2, reg bit 1)
            s0 = (lane & 2) ? a0 : a2;
            s1 = (lane & 2) ? a1 : a3;
            t0 = __shfl_xor(s0, 2, 64);
            t1 = __shfl_xor(s1, 2, 64);
            if (lane & 2) { a0 = t0; a1 = t1; } else { a2 = t0; a3 = t1; }
            // a0..a3 = pre-activation i,f,g,o for (local row, local f-col)
            const float iv = sigmoidf_fast(a0);
            const float fv = sigmoidf_fast(a1);
            const float gv = tanhf_fast(a2);
            const float ov = sigmoidf_fast(a3);
            const int lr = wmi * 128 + mt * 16 + quad * 4 + l3;   // 0..255
            const int lc = wni * 16 + nt * 4 + fl;                // 0..63
            const float cp = cbuf[lr * CB_STR + lc];
            const float cv = fv * cp + iv * gv;
            cbuf[lr * CB_STR + lc] = ov * tanhf_fast(cv);         // same-lane cell, no race
        }
    }
    __syncthreads();

    // ---- coalesced h store ----
#pragma unroll
    for (int i = 0; i < 8; ++i) {
        const int q  = i * 512 + tid;
        const int r  = q >> 4;
        const int c4 = (q & 15) << 2;
        *(float4*)&out[(long)(m0 + r) * F_DIM + fbase + c4] =
            *(const float4*)&cbuf[r * CB_STR + c4];
    }
}

// ---------------------------------------------------------------------------
// Inputs (setup_inputs order): behavior, h_prev, c_prev, Wh, Wx, b  (all fp32)
// Output: h (N_ROWS x F_DIM fp32)
// Workspace: A bf16 48 MB | W' bf16 12 MB | b' 16 KB
// ---------------------------------------------------------------------------
extern "C" void kernel_launch(void* const* d_in, const int* in_sizes, int n_in,
                              void* d_out, int out_size, void* d_ws, size_t ws_size,
                              hipStream_t stream) {
    const float* behavior = (const float*)d_in[0];
    const float* h_prev   = (const float*)d_in[1];
    const float* c_prev   = (const float*)d_in[2];
    const float* Wh       = (const float*)d_in[3];
    const float* Wx       = (const float*)d_in[4];
    const float* b        = (const float*)d_in[5];
    float* out = (float*)d_out;

    unsigned short* A  = (unsigned short*)d_ws;
    unsigned short* W  = A + (size_t)N_ROWS * K_DIM;
    float*       bperm = (float*)(W + (size_t)G_DIM * K_DIM);

    // Raise dynamic-LDS cap every call (cheap host-side call; no stream ops,
    // safe under graph capture).
    hipFuncSetAttribute(reinterpret_cast<const void*>(lstm_gemm),
                        hipFuncAttributeMaxDynamicSharedMemorySize, 131072);

    pack_all<<<N_ROWS + G_DIM, 192, 0, stream>>>(behavior, h_prev, Wh, Wx, b, A, W, bperm);
    lstm_gemm<<<dim3((N_ROWS / 256) * (G_DIM / 256)), 512, 131072, stream>>>(A, W, bperm, c_prev, out);
}